// Round 5
// baseline (331.989 us; speedup 1.0000x reference)
//
#include <hip/hip_runtime.h>
#include <math.h>

#define IN_CH   256
#define NCLS    21
#define ROIW    7
#define NPROP   128
#define BATCH   2
#define NROI    (BATCH*NPROP)        // 256
#define FEAT_DIM (IN_CH*ROIW*ROIW)   // 12544
#define HID     1024
#define NCAND   (NPROP*(NCLS-1))     // 2560 per image
#define MAXDET  100
#define SCORE_T 0.05f
#define NMS_T   0.5f

// ---------------- feature transpose: [img][c][pos] -> [img][pos][c] ----------------
__global__ __launch_bounds__(256) void transpose_feat(const float* __restrict__ feat,
                                                      float* __restrict__ ft) {
    int img = blockIdx.z;
    int cb = blockIdx.y;     // 8 blocks of 32 channels
    int pb = blockIdx.x;     // 32 blocks of 32 positions
    __shared__ float t[32][33];
    int tx = threadIdx.x & 31, ty = threadIdx.x >> 5;  // ty 0..7
#pragma unroll
    for (int i = 0; i < 4; ++i) {
        int c = ty + i * 8;
        t[c][tx] = feat[(size_t)img * 262144 + (size_t)(cb * 32 + c) * 1024 + pb * 32 + tx];
    }
    __syncthreads();
#pragma unroll
    for (int i = 0; i < 4; ++i) {
        int p = ty + i * 8;
        ft[(size_t)img * 262144 + (size_t)(pb * 32 + p) * 256 + cb * 32 + tx] = t[tx][p];
    }
}

// ---------------- RoIAlign on transposed features (fully coalesced) ----------------
__global__ __launch_bounds__(256) void roi_align_tr(const float* __restrict__ ft,
                                                    const float* __restrict__ props,
                                                    float* __restrict__ out) {
    int n = blockIdx.x >> 1;
    int half = blockIdx.x & 1;
    int img = n / NPROP;
    int q0 = half ? 25 : 0;
    int nq = half ? 24 : 25;
    const float* pr = props + n * 4;
    float x1 = pr[0] * 0.03125f, y1 = pr[1] * 0.03125f;
    float x2 = pr[2] * 0.03125f, y2 = pr[3] * 0.03125f;
    float rw = fmaxf(x2 - x1, 1.0f), rh = fmaxf(y2 - y1, 1.0f);
    float bw = rw / 7.0f, bh = rh / 7.0f;
    int cg = threadIdx.x & 63;   // channel group: channels cg*4..cg*4+3
    int qg = threadIdx.x >> 6;   // wave id 0..3
    __shared__ float tile[25][260];
    const float* base = ft + (size_t)img * 262144 + cg * 4;
    for (int j = qg; j < nq; j += 4) {
        int q = q0 + j;
        int iy = q / 7, ix = q % 7;
        float ax = 0.f, ay = 0.f, az = 0.f, aw = 0.f;
#pragma unroll
        for (int s = 0; s < 4; ++s) {
            int sy = s >> 1, sx = s & 1;
            float gy = (float)iy + ((float)sy + 0.5f) / 2.0f;
            float gx = (float)ix + ((float)sx + 0.5f) / 2.0f;
            float y = y1 + gy * bh;
            float x = x1 + gx * bw;
            bool inb = (y >= -1.0f) && (y <= 32.0f) && (x >= -1.0f) && (x <= 32.0f);
            float yc = fminf(fmaxf(y, 0.0f), 31.0f);
            float xc = fminf(fmaxf(x, 0.0f), 31.0f);
            float y0f = floorf(yc), x0f = floorf(xc);
            int y0 = (int)y0f, x0i = (int)x0f;
            int y1i = min(y0 + 1, 31), x1i = min(x0i + 1, 31);
            float ly = yc - y0f, lx = xc - x0f;
            float hy = 1.0f - ly, hx = 1.0f - lx;
            float wg = inb ? 1.0f : 0.0f;
            float w00 = hy * hx * wg, w01 = hy * lx * wg, w10 = ly * hx * wg, w11 = ly * lx * wg;
            float4 f00 = *(const float4*)(base + (size_t)(y0 * 32 + x0i) * 256);
            float4 f01 = *(const float4*)(base + (size_t)(y0 * 32 + x1i) * 256);
            float4 f10 = *(const float4*)(base + (size_t)(y1i * 32 + x0i) * 256);
            float4 f11 = *(const float4*)(base + (size_t)(y1i * 32 + x1i) * 256);
            ax += w00 * f00.x + w01 * f01.x + w10 * f10.x + w11 * f11.x;
            ay += w00 * f00.y + w01 * f01.y + w10 * f10.y + w11 * f11.y;
            az += w00 * f00.z + w01 * f01.z + w10 * f10.z + w11 * f11.z;
            aw += w00 * f00.w + w01 * f01.w + w10 * f10.w + w11 * f11.w;
        }
        *(float4*)&tile[j][cg * 4] = make_float4(ax * 0.25f, ay * 0.25f, az * 0.25f, aw * 0.25f);
    }
    __syncthreads();
    float* ob = out + (size_t)n * FEAT_DIM + q0;
    int tid = threadIdx.x;
    if (half == 0) {
        for (int i = tid; i < 256 * 25; i += 256) {
            int c = i / 25, ql = i % 25;
            ob[c * 49 + ql] = tile[ql][c];
        }
    } else {
        for (int i = tid; i < 256 * 24; i += 256) {
            int c = i / 24, ql = i % 24;
            ob[c * 49 + ql] = tile[ql][c];
        }
    }
}

// ---------------- GEMM: C_part[s] = A[Nr,K] * W[Mo,K]^T (k-chunk s) ----------------
// 128x128 tile, 8x8 micro-tile (split 4+4 at +64: 16B lane stride -> 2-way bank = free)
#define GBM 128
#define GBN 128
#define GBK 16
__global__ __launch_bounds__(256) void gemm_tn_part(const float* __restrict__ A,
                                                    const float* __restrict__ Wt,
                                                    float* __restrict__ Cp,
                                                    int Nr, int Mo, int K) {
    const int S = gridDim.z;
    const int kchunk = K / S;
    const int k0 = blockIdx.z * kchunk;
    const int n0 = blockIdx.y * GBM;
    const int j0 = blockIdx.x * GBN;
    __shared__ float As[GBK][GBM + 4];
    __shared__ float Ws[GBK][GBN + 4];
    const int tid = threadIdx.x;
    const int tx = tid & 15;
    const int ty = tid >> 4;
    const int r0 = tx << 2;           // rows r0..r0+3 and r0+64..r0+67
    const int c0 = ty << 2;           // cols c0..c0+3 and c0+64..c0+67
    const int srow = tid >> 1;        // 0..127 (staging row)
    const int skk = (tid & 1) << 3;   // 0 or 8
    float acc[8][8];
#pragma unroll
    for (int r = 0; r < 8; ++r)
#pragma unroll
        for (int c = 0; c < 8; ++c) acc[r][c] = 0.0f;

    const int iters = kchunk / GBK;
    const float* Abase = A + (size_t)(n0 + srow) * K + skk;
    const float* Wbase = Wt + (size_t)(j0 + srow) * K + skk;
    float4 pa0 = *(const float4*)(Abase + k0);
    float4 pa1 = *(const float4*)(Abase + k0 + 4);
    float4 pw0 = *(const float4*)(Wbase + k0);
    float4 pw1 = *(const float4*)(Wbase + k0 + 4);

#pragma unroll 1
    for (int it = 0; it < iters; ++it) {
        __syncthreads();
        As[skk + 0][srow] = pa0.x; As[skk + 1][srow] = pa0.y; As[skk + 2][srow] = pa0.z; As[skk + 3][srow] = pa0.w;
        As[skk + 4][srow] = pa1.x; As[skk + 5][srow] = pa1.y; As[skk + 6][srow] = pa1.z; As[skk + 7][srow] = pa1.w;
        Ws[skk + 0][srow] = pw0.x; Ws[skk + 1][srow] = pw0.y; Ws[skk + 2][srow] = pw0.z; Ws[skk + 3][srow] = pw0.w;
        Ws[skk + 4][srow] = pw1.x; Ws[skk + 5][srow] = pw1.y; Ws[skk + 6][srow] = pw1.z; Ws[skk + 7][srow] = pw1.w;
        __syncthreads();
        if (it + 1 < iters) {
            int kc = k0 + (it + 1) * GBK;
            pa0 = *(const float4*)(Abase + kc);
            pa1 = *(const float4*)(Abase + kc + 4);
            pw0 = *(const float4*)(Wbase + kc);
            pw1 = *(const float4*)(Wbase + kc + 4);
        }
#pragma unroll
        for (int k = 0; k < GBK; ++k) {
            float4 t0 = *(const float4*)&As[k][r0];
            float4 t1 = *(const float4*)&As[k][r0 + 64];
            float4 u0 = *(const float4*)&Ws[k][c0];
            float4 u1 = *(const float4*)&Ws[k][c0 + 64];
            float a[8] = {t0.x, t0.y, t0.z, t0.w, t1.x, t1.y, t1.z, t1.w};
            float w[8] = {u0.x, u0.y, u0.z, u0.w, u1.x, u1.y, u1.z, u1.w};
#pragma unroll
            for (int r = 0; r < 8; ++r)
#pragma unroll
                for (int c = 0; c < 8; ++c)
                    acc[r][c] = fmaf(a[r], w[c], acc[r][c]);
        }
    }
#pragma unroll
    for (int r = 0; r < 8; ++r) {
        int gr = n0 + ((r < 4) ? (r0 + r) : (r0 + 64 + r - 4));
        float* o = Cp + ((size_t)blockIdx.z * Nr + gr) * Mo + j0;
        *(float4*)(o + c0)      = make_float4(acc[r][0], acc[r][1], acc[r][2], acc[r][3]);
        *(float4*)(o + c0 + 64) = make_float4(acc[r][4], acc[r][5], acc[r][6], acc[r][7]);
    }
}

// ---------------- reduce split-K partials + bias + relu ----------------
__global__ __launch_bounds__(256) void reduce_bias_relu(const float* __restrict__ Cp,
                                                        const float* __restrict__ bias,
                                                        float* __restrict__ X,
                                                        int Nr, int Mo, int S) {
    int idx = blockIdx.x * 256 + threadIdx.x;
    int total = (Nr * Mo) >> 2;
    if (idx >= total) return;
    int e = idx << 2;
    int j = e % Mo;
    float4 s = make_float4(0.f, 0.f, 0.f, 0.f);
    for (int ss = 0; ss < S; ++ss) {
        float4 c = *(const float4*)(Cp + (size_t)ss * Nr * Mo + e);
        s.x += c.x; s.y += c.y; s.z += c.z; s.w += c.w;
    }
    float4 b = *(const float4*)(bias + j);
    s.x = fmaxf(s.x + b.x, 0.f); s.y = fmaxf(s.y + b.y, 0.f);
    s.z = fmaxf(s.z + b.z, 0.f); s.w = fmaxf(s.w + b.w, 0.f);
    *(float4*)(X + e) = s;
}

// ---------------- heads: one wave per output row, coalesced, shfl-reduce ----------------
__global__ __launch_bounds__(256) void heads_k(const float* __restrict__ X2,
                                               const float* __restrict__ Wc, const float* __restrict__ bc,
                                               const float* __restrict__ Wb, const float* __restrict__ bb,
                                               float* __restrict__ probs, float* __restrict__ breg) {
    int n = blockIdx.x;
    int tid = threadIdx.x;
    __shared__ float xs[HID];
    __shared__ float lg[NCLS];
    __shared__ float ssum;
    *(float4*)&xs[tid * 4] = *(const float4*)(X2 + (size_t)n * HID + tid * 4);
    __syncthreads();
    int wave = tid >> 6, lane = tid & 63;
    for (int h = wave; h < 105; h += 4) {
        const float* w = (h < 21) ? (Wc + (size_t)h * HID) : (Wb + (size_t)(h - 21) * HID);
        float acc = 0.0f;
#pragma unroll
        for (int k0 = 0; k0 < HID; k0 += 256) {
            float4 wv = *(const float4*)(w + k0 + lane * 4);
            float4 xv = *(const float4*)&xs[k0 + lane * 4];
            acc = fmaf(wv.x, xv.x, acc);
            acc = fmaf(wv.y, xv.y, acc);
            acc = fmaf(wv.z, xv.z, acc);
            acc = fmaf(wv.w, xv.w, acc);
        }
#pragma unroll
        for (int m = 32; m; m >>= 1) acc += __shfl_xor(acc, m, 64);
        if (lane == 0) {
            if (h < 21) lg[h] = acc + bc[h];
            else breg[(size_t)n * 84 + (h - 21)] = acc + bb[h - 21];
        }
    }
    __syncthreads();
    if (tid == 0) {
        float m = lg[0];
        for (int c = 1; c < 21; ++c) m = fmaxf(m, lg[c]);
        float s = 0.0f;
        for (int c = 0; c < 21; ++c) { float e = expf(lg[c] - m); lg[c] = e; s += e; }
        ssum = s;
    }
    __syncthreads();
    if (tid < 21) probs[(size_t)n * 21 + tid] = lg[tid] / ssum;
}

// ---------------- candidates: decode, clip, score/key (+ vcnt init) ----------------
__global__ __launch_bounds__(256) void cand_k(const float* __restrict__ props,
                                              const int* __restrict__ img_sizes,
                                              const float* __restrict__ probs,
                                              const float* __restrict__ breg,
                                              float* __restrict__ cbox,
                                              float* __restrict__ csc,
                                              unsigned long long* __restrict__ ckey,
                                              int* __restrict__ vcount) {
    int t = blockIdx.x * 256 + threadIdx.x;
    if (blockIdx.x == 0 && threadIdx.x < 2) vcount[threadIdx.x] = 0;
    if (t >= BATCH * NCAND) return;
    int img = t / NCAND, m = t % NCAND;
    int p = m / 20, c = m % 20 + 1;
    int row = img * NPROP + p;
    float s = probs[(size_t)row * 21 + c];
    const float* pr = props + row * 4;
    float pw = pr[2] - pr[0], ph = pr[3] - pr[1];
    float px = pr[0] + pw * 0.5f, py = pr[1] + ph * 0.5f;
    const float* d = breg + (size_t)row * 84 + c * 4;
    float cx = px + d[0] * pw;
    float cy = py + d[1] * ph;
    float w = pw * expf(d[2]);
    float h = ph * expf(d[3]);
    float bx1 = cx - w * 0.5f, by1 = cy - h * 0.5f, bx2 = cx + w * 0.5f, by2 = cy + h * 0.5f;
    float Wi = (float)img_sizes[img * 2 + 1], Hi = (float)img_sizes[img * 2 + 0];
    bx1 = fminf(fmaxf(bx1, 0.f), Wi); by1 = fminf(fmaxf(by1, 0.f), Hi);
    bx2 = fminf(fmaxf(bx2, 0.f), Wi); by2 = fminf(fmaxf(by2, 0.f), Hi);
    *(float4*)(cbox + (size_t)t * 4) = make_float4(bx1, by1, bx2, by2);
    csc[t] = s;
    bool valid = s > SCORE_T;
    unsigned int sb = __float_as_uint(s);  // s>0 -> monotonic bits
    ckey[t] = valid ? (((unsigned long long)sb << 32) | (unsigned int)(NCAND - 1 - m)) : 0ull;
}

// ---------------- rank: uniform-j broadcast compares, 80 blocks ----------------
__global__ __launch_bounds__(256) void rank_k(const float* __restrict__ cbox,
                                              const float* __restrict__ csc,
                                              const unsigned long long* __restrict__ ckey,
                                              float* __restrict__ sbox, float* __restrict__ ssc,
                                              int* __restrict__ sm, int* __restrict__ vcount) {
    int img = blockIdx.x / 40;
    int seg = blockIdx.x % 40;
    int base = img * NCAND;
    int lm = threadIdx.x & 63;
    int chunk = threadIdx.x >> 6;
    int m = seg * 64 + lm;
    __shared__ __align__(16) unsigned long long keys[NCAND];   // 20.5 KB
    for (int j = threadIdx.x; j < NCAND; j += 256) keys[j] = ckey[base + j];
    unsigned long long mykey = ckey[base + m];
    float s = csc[base + m];
    bool valid = s > SCORE_T;
    __syncthreads();
    const ulonglong2* kp = (const ulonglong2*)&keys[chunk * 640];
    int r = 0;
#pragma unroll 4
    for (int j = 0; j < 320; ++j) {
        ulonglong2 kk = kp[j];
        r += (kk.x > mykey) ? 1 : 0;
        r += (kk.y > mykey) ? 1 : 0;
    }
    __shared__ int part[4][64];
    part[chunk][lm] = r;
    __syncthreads();
    if (chunk == 0) {
        int rank = part[0][lm] + part[1][lm] + part[2][lm] + part[3][lm];
        if (valid) {
            int o = base + rank;
            *(float4*)(sbox + (size_t)o * 4) = *(const float4*)(cbox + (size_t)(base + m) * 4);
            ssc[o] = s;
            sm[o] = m;
        }
    }
    int cnt = __syncthreads_count((chunk == 0) && valid);
    if (threadIdx.x == 0) atomicAdd(&vcount[img], cnt);
}

// ---------------- per-(image,class) greedy NMS ----------------
__global__ __launch_bounds__(64) void nms_k(const int* __restrict__ sm,
                                            const float* __restrict__ sbox,
                                            const int* __restrict__ vcount,
                                            int* __restrict__ skeep) {
    int bid = blockIdx.x;
    int img = bid / 20;
    int cls = bid % 20 + 1;
    int V = vcount[img];
    __shared__ float lx1[128], ly1[128], lx2[128], ly2[128];
    __shared__ int lpos[128];
    __shared__ int lcnt;
    __shared__ int keepL[128];
    int lane = threadIdx.x;
    if (lane == 0) lcnt = 0;
    __syncthreads();
    for (int p0 = 0; p0 < V; p0 += 64) {
        int p = p0 + lane;
        bool pred = false;
        if (p < V) {
            int m = sm[img * NCAND + p];
            pred = (m % 20 + 1) == cls;
        }
        unsigned long long mask = __ballot(pred);
        int base = lcnt;
        if (pred) {
            int idx = base + __popcll(mask & ((1ull << lane) - 1ull));
            const float* bx = sbox + (size_t)(img * NCAND + (p0 + lane)) * 4;
            lx1[idx] = bx[0]; ly1[idx] = bx[1]; lx2[idx] = bx[2]; ly2[idx] = bx[3];
            lpos[idx] = p0 + lane;
        }
        __syncthreads();
        if (lane == 0) lcnt += (int)__popcll(mask);
        __syncthreads();
    }
    int C = lcnt;
    for (int j = lane; j < 128; j += 64) keepL[j] = 1;
    __syncthreads();
    for (int i = 0; i < C; ++i) {
        __syncthreads();
        if (keepL[i] == 0) continue;
        float X1 = lx1[i], Y1 = ly1[i], X2 = lx2[i], Y2 = ly2[i];
        float ai = (X2 - X1) * (Y2 - Y1);
        for (int j = i + 1 + lane; j < C; j += 64) {
            if (keepL[j]) {
                float xi1 = fmaxf(X1, lx1[j]);
                float yi1 = fmaxf(Y1, ly1[j]);
                float xi2 = fminf(X2, lx2[j]);
                float yi2 = fminf(Y2, ly2[j]);
                float inter = fmaxf(xi2 - xi1, 0.f) * fmaxf(yi2 - yi1, 0.f);
                float aj = (lx2[j] - lx1[j]) * (ly2[j] - ly1[j]);
                float iou = inter / (ai + aj - inter + 1e-9f);
                if (iou > NMS_T) keepL[j] = 0;
            }
        }
    }
    __syncthreads();
    for (int j = lane; j < C; j += 64) skeep[img * NCAND + lpos[j]] = keepL[j];
}

// ---------------- writer: prefix-scan kept, emit top-100 ----------------
__global__ __launch_bounds__(256) void write_k(const float* __restrict__ sbox,
                                               const float* __restrict__ ssc,
                                               const int* __restrict__ sm,
                                               const int* __restrict__ skeep,
                                               const int* __restrict__ vcount,
                                               float* __restrict__ out) {
    int img = blockIdx.x;
    int tid = threadIdx.x;
    float* ob = out + img * MAXDET * 4;
    float* os = out + BATCH * MAXDET * 4 + img * MAXDET;
    float* ol = out + BATCH * MAXDET * 5 + img * MAXDET;
    for (int i = tid; i < MAXDET * 4; i += 256) ob[i] = 0.0f;
    for (int i = tid; i < MAXDET; i += 256) { os[i] = 0.0f; ol[i] = 0.0f; }
    __syncthreads();
    int V = vcount[img];
    int chunk = (V + 255) / 256;
    int lo = tid * chunk, hi = min(lo + chunk, V);
    int cnt = 0;
    for (int p = lo; p < hi; ++p) cnt += skeep[img * NCAND + p];
    __shared__ int cs[256];
    __shared__ int pre[256];
    cs[tid] = cnt;
    __syncthreads();
    if (tid == 0) {
        int run = 0;
        for (int t = 0; t < 256; ++t) { pre[t] = run; run += cs[t]; }
    }
    __syncthreads();
    int r = pre[tid];
    for (int p = lo; p < hi; ++p) {
        if (skeep[img * NCAND + p]) {
            if (r < MAXDET) {
                const float* bx = sbox + (size_t)(img * NCAND + p) * 4;
                ob[r * 4 + 0] = bx[0]; ob[r * 4 + 1] = bx[1];
                ob[r * 4 + 2] = bx[2]; ob[r * 4 + 3] = bx[3];
                os[r] = ssc[img * NCAND + p];
                ol[r] = (float)(sm[img * NCAND + p] % 20 + 1);
            }
            ++r;
        }
    }
}

extern "C" void kernel_launch(void* const* d_in, const int* in_sizes, int n_in,
                              void* d_out, int out_size, void* d_ws, size_t ws_size,
                              hipStream_t stream) {
    const float* features  = (const float*)d_in[0];
    const float* proposals = (const float*)d_in[1];
    const int*   img_sizes = (const int*)d_in[2];
    const float* W1 = (const float*)d_in[3];
    const float* b1 = (const float*)d_in[4];
    const float* W2 = (const float*)d_in[5];
    const float* b2 = (const float*)d_in[6];
    const float* Wc = (const float*)d_in[7];
    const float* bc = (const float*)d_in[8];
    const float* Wb = (const float*)d_in[9];
    const float* bb = (const float*)d_in[10];
    float* out = (float*)d_out;

    // split-K factor for FC1 chosen from workspace budget (constant across calls
    // -> graph-stable). 12544/49 = 256 (16 GBK iters); 784 blocks ~ 3/CU.
    float* ws = (float*)d_ws;
    size_t fixed = 3211264 + 262144 + 262144;            // roi + x1 + x2
    size_t tail  = 5376 + 21504 + 20480 + 5120 + 10240 + 20480 + 5120 + 5120 + 5120 + 64;
    int S1 = ((fixed + (size_t)49 * 262144 + tail) * 4 <= ws_size) ? 49 : 16;

    float* roi   = ws;                        // 256*12544
    float* x1    = roi + 3211264;
    float* x2    = x1 + 262144;
    float* cpart = x2 + 262144;               // S1 * 262144
    float* featT = cpart;                     // aliases cpart: dead before FC1 writes it
    float* probs = cpart + (size_t)S1 * 262144;
    float* breg  = probs + 5376;
    float* cbox  = breg + 21504;
    float* csc   = cbox + 20480;
    unsigned long long* ckey = (unsigned long long*)(csc + 5120);
    float* sbox  = csc + 5120 + 10240;
    float* ssc   = sbox + 20480;
    int*   sm    = (int*)(ssc + 5120);
    int*   skeep = sm + 5120;
    int*   vcnt  = skeep + 5120;

    hipLaunchKernelGGL(transpose_feat, dim3(32, 8, 2), dim3(256), 0, stream, features, featT);
    hipLaunchKernelGGL(roi_align_tr, dim3(NROI * 2), dim3(256), 0, stream, featT, proposals, roi);
    // FC1: 256 x 12544 -> 1024, tile 128x128, split-K=S1
    hipLaunchKernelGGL(gemm_tn_part, dim3(8, 2, S1), dim3(256), 0, stream, roi, W1, cpart, NROI, HID, FEAT_DIM);
    hipLaunchKernelGGL(reduce_bias_relu, dim3(256), dim3(256), 0, stream, cpart, b1, x1, NROI, HID, S1);
    // FC2: 256 x 1024 -> 1024, split-K=16
    hipLaunchKernelGGL(gemm_tn_part, dim3(8, 2, 16), dim3(256), 0, stream, x1, W2, cpart, NROI, HID, HID);
    hipLaunchKernelGGL(reduce_bias_relu, dim3(256), dim3(256), 0, stream, cpart, b2, x2, NROI, HID, 16);
    hipLaunchKernelGGL(heads_k, dim3(NROI), dim3(256), 0, stream, x2, Wc, bc, Wb, bb, probs, breg);
    hipLaunchKernelGGL(cand_k, dim3((BATCH * NCAND + 255) / 256), dim3(256), 0, stream,
                       proposals, img_sizes, probs, breg, cbox, csc, ckey, vcnt);
    hipLaunchKernelGGL(rank_k, dim3(80), dim3(256), 0, stream, cbox, csc, ckey, sbox, ssc, sm, vcnt);
    hipLaunchKernelGGL(nms_k, dim3(BATCH * 20), dim3(64), 0, stream, sm, sbox, vcnt, skeep);
    hipLaunchKernelGGL(write_k, dim3(BATCH), dim3(256), 0, stream, sbox, ssc, sm, skeep, vcnt, out);
}

// Round 6
// 319.878 us; speedup vs baseline: 1.0379x; 1.0379x over previous
//
#include <hip/hip_runtime.h>
#include <math.h>

#define IN_CH   256
#define NCLS    21
#define ROIW    7
#define NPROP   128
#define BATCH   2
#define NROI    (BATCH*NPROP)        // 256
#define FEAT_DIM (IN_CH*ROIW*ROIW)   // 12544
#define HID     1024
#define NCAND   (NPROP*(NCLS-1))     // 2560 per image
#define MAXDET  100
#define SCORE_T 0.05f
#define NMS_T   0.5f

// ---------------- feature transpose: [img][c][pos] -> [img][pos][c] ----------------
__global__ __launch_bounds__(256) void transpose_feat(const float* __restrict__ feat,
                                                      float* __restrict__ ft) {
    int img = blockIdx.z;
    int cb = blockIdx.y;
    int pb = blockIdx.x;
    __shared__ float t[32][33];
    int tx = threadIdx.x & 31, ty = threadIdx.x >> 5;
#pragma unroll
    for (int i = 0; i < 4; ++i) {
        int c = ty + i * 8;
        t[c][tx] = feat[(size_t)img * 262144 + (size_t)(cb * 32 + c) * 1024 + pb * 32 + tx];
    }
    __syncthreads();
#pragma unroll
    for (int i = 0; i < 4; ++i) {
        int p = ty + i * 8;
        ft[(size_t)img * 262144 + (size_t)(pb * 32 + p) * 256 + cb * 32 + tx] = t[tx][p];
    }
}

// ---------------- RoIAlign on transposed features (fully coalesced) ----------------
__global__ __launch_bounds__(256) void roi_align_tr(const float* __restrict__ ft,
                                                    const float* __restrict__ props,
                                                    float* __restrict__ out) {
    int n = blockIdx.x >> 1;
    int half = blockIdx.x & 1;
    int img = n / NPROP;
    int q0 = half ? 25 : 0;
    int nq = half ? 24 : 25;
    const float* pr = props + n * 4;
    float x1 = pr[0] * 0.03125f, y1 = pr[1] * 0.03125f;
    float x2 = pr[2] * 0.03125f, y2 = pr[3] * 0.03125f;
    float rw = fmaxf(x2 - x1, 1.0f), rh = fmaxf(y2 - y1, 1.0f);
    float bw = rw / 7.0f, bh = rh / 7.0f;
    int cg = threadIdx.x & 63;
    int qg = threadIdx.x >> 6;
    __shared__ float tile[25][260];
    const float* base = ft + (size_t)img * 262144 + cg * 4;
    for (int j = qg; j < nq; j += 4) {
        int q = q0 + j;
        int iy = q / 7, ix = q % 7;
        float ax = 0.f, ay = 0.f, az = 0.f, aw = 0.f;
#pragma unroll
        for (int s = 0; s < 4; ++s) {
            int sy = s >> 1, sx = s & 1;
            float gy = (float)iy + ((float)sy + 0.5f) / 2.0f;
            float gx = (float)ix + ((float)sx + 0.5f) / 2.0f;
            float y = y1 + gy * bh;
            float x = x1 + gx * bw;
            bool inb = (y >= -1.0f) && (y <= 32.0f) && (x >= -1.0f) && (x <= 32.0f);
            float yc = fminf(fmaxf(y, 0.0f), 31.0f);
            float xc = fminf(fmaxf(x, 0.0f), 31.0f);
            float y0f = floorf(yc), x0f = floorf(xc);
            int y0 = (int)y0f, x0i = (int)x0f;
            int y1i = min(y0 + 1, 31), x1i = min(x0i + 1, 31);
            float ly = yc - y0f, lx = xc - x0f;
            float hy = 1.0f - ly, hx = 1.0f - lx;
            float wg = inb ? 1.0f : 0.0f;
            float w00 = hy * hx * wg, w01 = hy * lx * wg, w10 = ly * hx * wg, w11 = ly * lx * wg;
            float4 f00 = *(const float4*)(base + (size_t)(y0 * 32 + x0i) * 256);
            float4 f01 = *(const float4*)(base + (size_t)(y0 * 32 + x1i) * 256);
            float4 f10 = *(const float4*)(base + (size_t)(y1i * 32 + x0i) * 256);
            float4 f11 = *(const float4*)(base + (size_t)(y1i * 32 + x1i) * 256);
            ax += w00 * f00.x + w01 * f01.x + w10 * f10.x + w11 * f11.x;
            ay += w00 * f00.y + w01 * f01.y + w10 * f10.y + w11 * f11.y;
            az += w00 * f00.z + w01 * f01.z + w10 * f10.z + w11 * f11.z;
            aw += w00 * f00.w + w01 * f01.w + w10 * f10.w + w11 * f11.w;
        }
        *(float4*)&tile[j][cg * 4] = make_float4(ax * 0.25f, ay * 0.25f, az * 0.25f, aw * 0.25f);
    }
    __syncthreads();
    float* ob = out + (size_t)n * FEAT_DIM + q0;
    int tid = threadIdx.x;
    if (half == 0) {
        for (int i = tid; i < 256 * 25; i += 256) {
            int c = i / 25, ql = i % 25;
            ob[c * 49 + ql] = tile[ql][c];
        }
    } else {
        for (int i = tid; i < 256 * 24; i += 256) {
            int c = i / 24, ql = i % 24;
            ob[c * 49 + ql] = tile[ql][c];
        }
    }
}

// ---------------- GEMM: C_part[s] = A[Nr,K] * W[Mo,K]^T (k-chunk s) ----------------
// 128x128 tile, 8x8 micro-tile, global-register prefetch + LDS-fragment register
// double-buffer (hide ds_read latency at 1 wave/SIMD)
#define GBM 128
#define GBN 128
#define GBK 16
__global__ __launch_bounds__(256) void gemm_tn_part(const float* __restrict__ A,
                                                    const float* __restrict__ Wt,
                                                    float* __restrict__ Cp,
                                                    int Nr, int Mo, int K) {
    const int S = gridDim.z;
    const int kchunk = K / S;
    const int k0 = blockIdx.z * kchunk;
    const int n0 = blockIdx.y * GBM;
    const int j0 = blockIdx.x * GBN;
    __shared__ float As[GBK][GBM + 4];
    __shared__ float Ws[GBK][GBN + 4];
    const int tid = threadIdx.x;
    const int tx = tid & 15;
    const int ty = tid >> 4;
    const int r0 = tx << 2;
    const int c0 = ty << 2;
    const int srow = tid >> 1;
    const int skk = (tid & 1) << 3;
    float acc[8][8];
#pragma unroll
    for (int r = 0; r < 8; ++r)
#pragma unroll
        for (int c = 0; c < 8; ++c) acc[r][c] = 0.0f;

    const int iters = kchunk / GBK;
    const float* Abase = A + (size_t)(n0 + srow) * K + skk;
    const float* Wbase = Wt + (size_t)(j0 + srow) * K + skk;
    float4 pa0 = *(const float4*)(Abase + k0);
    float4 pa1 = *(const float4*)(Abase + k0 + 4);
    float4 pw0 = *(const float4*)(Wbase + k0);
    float4 pw1 = *(const float4*)(Wbase + k0 + 4);

#pragma unroll 1
    for (int it = 0; it < iters; ++it) {
        __syncthreads();
        As[skk + 0][srow] = pa0.x; As[skk + 1][srow] = pa0.y; As[skk + 2][srow] = pa0.z; As[skk + 3][srow] = pa0.w;
        As[skk + 4][srow] = pa1.x; As[skk + 5][srow] = pa1.y; As[skk + 6][srow] = pa1.z; As[skk + 7][srow] = pa1.w;
        Ws[skk + 0][srow] = pw0.x; Ws[skk + 1][srow] = pw0.y; Ws[skk + 2][srow] = pw0.z; Ws[skk + 3][srow] = pw0.w;
        Ws[skk + 4][srow] = pw1.x; Ws[skk + 5][srow] = pw1.y; Ws[skk + 6][srow] = pw1.z; Ws[skk + 7][srow] = pw1.w;
        __syncthreads();
        if (it + 1 < iters) {
            int kc = k0 + (it + 1) * GBK;
            pa0 = *(const float4*)(Abase + kc);
            pa1 = *(const float4*)(Abase + kc + 4);
            pw0 = *(const float4*)(Wbase + kc);
            pw1 = *(const float4*)(Wbase + kc + 4);
        }
        // register double-buffer over k-steps
        float4 fa0[2], fa1[2], fw0[2], fw1[2];
        fa0[0] = *(const float4*)&As[0][r0];
        fa1[0] = *(const float4*)&As[0][r0 + 64];
        fw0[0] = *(const float4*)&Ws[0][c0];
        fw1[0] = *(const float4*)&Ws[0][c0 + 64];
#pragma unroll
        for (int k = 0; k < GBK; ++k) {
            const int cur = k & 1, nxt = cur ^ 1;
            if (k + 1 < GBK) {
                fa0[nxt] = *(const float4*)&As[k + 1][r0];
                fa1[nxt] = *(const float4*)&As[k + 1][r0 + 64];
                fw0[nxt] = *(const float4*)&Ws[k + 1][c0];
                fw1[nxt] = *(const float4*)&Ws[k + 1][c0 + 64];
            }
            float a[8] = {fa0[cur].x, fa0[cur].y, fa0[cur].z, fa0[cur].w,
                          fa1[cur].x, fa1[cur].y, fa1[cur].z, fa1[cur].w};
            float w[8] = {fw0[cur].x, fw0[cur].y, fw0[cur].z, fw0[cur].w,
                          fw1[cur].x, fw1[cur].y, fw1[cur].z, fw1[cur].w};
#pragma unroll
            for (int r = 0; r < 8; ++r)
#pragma unroll
                for (int c = 0; c < 8; ++c)
                    acc[r][c] = fmaf(a[r], w[c], acc[r][c]);
        }
    }
#pragma unroll
    for (int r = 0; r < 8; ++r) {
        int gr = n0 + ((r < 4) ? (r0 + r) : (r0 + 64 + r - 4));
        float* o = Cp + ((size_t)blockIdx.z * Nr + gr) * Mo + j0;
        *(float4*)(o + c0)      = make_float4(acc[r][0], acc[r][1], acc[r][2], acc[r][3]);
        *(float4*)(o + c0 + 64) = make_float4(acc[r][4], acc[r][5], acc[r][6], acc[r][7]);
    }
}

// ---------------- reduce split-K partials + bias + relu ----------------
__global__ __launch_bounds__(256) void reduce_bias_relu(const float* __restrict__ Cp,
                                                        const float* __restrict__ bias,
                                                        float* __restrict__ X,
                                                        int Nr, int Mo, int S) {
    int idx = blockIdx.x * 256 + threadIdx.x;
    int total = (Nr * Mo) >> 2;
    if (idx >= total) return;
    int e = idx << 2;
    int j = e % Mo;
    float4 s = make_float4(0.f, 0.f, 0.f, 0.f);
    for (int ss = 0; ss < S; ++ss) {
        float4 c = *(const float4*)(Cp + (size_t)ss * Nr * Mo + e);
        s.x += c.x; s.y += c.y; s.z += c.z; s.w += c.w;
    }
    float4 b = *(const float4*)(bias + j);
    s.x = fmaxf(s.x + b.x, 0.f); s.y = fmaxf(s.y + b.y, 0.f);
    s.z = fmaxf(s.z + b.z, 0.f); s.w = fmaxf(s.w + b.w, 0.f);
    *(float4*)(X + e) = s;
}

// ---------------- fused: reduce2 + heads + softmax + decode/clip/key ----------------
// one block per ROI row; x2 row built from cpart slices (identical order to
// reduce_bias_relu -> bit-identical), logits/softmax/breg in LDS, threads 0..19
// decode the 20 class candidates directly.
__global__ __launch_bounds__(256) void heads_cand_k(const float* __restrict__ Cp2,
                                                    const float* __restrict__ b2,
                                                    const float* __restrict__ Wc, const float* __restrict__ bc,
                                                    const float* __restrict__ Wb, const float* __restrict__ bb,
                                                    const float* __restrict__ props,
                                                    const int* __restrict__ img_sizes,
                                                    float* __restrict__ cbox,
                                                    float* __restrict__ csc,
                                                    unsigned long long* __restrict__ ckey,
                                                    int* __restrict__ vcount) {
    int n = blockIdx.x;
    int tid = threadIdx.x;
    if (n == 0 && tid < 2) vcount[tid] = 0;
    __shared__ float xs[HID];
    __shared__ float lg[NCLS];
    __shared__ float bs[84];
    __shared__ float ssum;
    // build x2 row: sum 16 cpart slices + bias + relu (order matches reduce_bias_relu)
    {
        int e = n * HID + tid * 4;
        float4 s = make_float4(0.f, 0.f, 0.f, 0.f);
#pragma unroll
        for (int ss = 0; ss < 16; ++ss) {
            float4 c = *(const float4*)(Cp2 + (size_t)ss * (NROI * HID) + e);
            s.x += c.x; s.y += c.y; s.z += c.z; s.w += c.w;
        }
        float4 b = *(const float4*)(b2 + tid * 4);
        s.x = fmaxf(s.x + b.x, 0.f); s.y = fmaxf(s.y + b.y, 0.f);
        s.z = fmaxf(s.z + b.z, 0.f); s.w = fmaxf(s.w + b.w, 0.f);
        *(float4*)&xs[tid * 4] = s;
    }
    __syncthreads();
    int wave = tid >> 6, lane = tid & 63;
    for (int h = wave; h < 105; h += 4) {
        const float* w = (h < 21) ? (Wc + (size_t)h * HID) : (Wb + (size_t)(h - 21) * HID);
        float acc = 0.0f;
#pragma unroll
        for (int k0 = 0; k0 < HID; k0 += 256) {
            float4 wv = *(const float4*)(w + k0 + lane * 4);
            float4 xv = *(const float4*)&xs[k0 + lane * 4];
            acc = fmaf(wv.x, xv.x, acc);
            acc = fmaf(wv.y, xv.y, acc);
            acc = fmaf(wv.z, xv.z, acc);
            acc = fmaf(wv.w, xv.w, acc);
        }
#pragma unroll
        for (int m = 32; m; m >>= 1) acc += __shfl_xor(acc, m, 64);
        if (lane == 0) {
            if (h < 21) lg[h] = acc + bc[h];
            else bs[h - 21] = acc + bb[h - 21];
        }
    }
    __syncthreads();
    if (tid == 0) {
        float m = lg[0];
        for (int c = 1; c < 21; ++c) m = fmaxf(m, lg[c]);
        float s = 0.0f;
        for (int c = 0; c < 21; ++c) { float e = expf(lg[c] - m); lg[c] = e; s += e; }
        ssum = s;
    }
    __syncthreads();
    if (tid < 20) {
        int c = tid + 1;
        int img = n / NPROP;
        float s = lg[c] / ssum;
        const float* pr = props + n * 4;
        float pw = pr[2] - pr[0], ph = pr[3] - pr[1];
        float px = pr[0] + pw * 0.5f, py = pr[1] + ph * 0.5f;
        const float* d = &bs[c * 4];
        float cx = px + d[0] * pw;
        float cy = py + d[1] * ph;
        float w = pw * expf(d[2]);
        float h = ph * expf(d[3]);
        float bx1 = cx - w * 0.5f, by1 = cy - h * 0.5f, bx2 = cx + w * 0.5f, by2 = cy + h * 0.5f;
        float Wi = (float)img_sizes[img * 2 + 1], Hi = (float)img_sizes[img * 2 + 0];
        bx1 = fminf(fmaxf(bx1, 0.f), Wi); by1 = fminf(fmaxf(by1, 0.f), Hi);
        bx2 = fminf(fmaxf(bx2, 0.f), Wi); by2 = fminf(fmaxf(by2, 0.f), Hi);
        int t = n * 20 + tid;                 // == img*NCAND + p*20 + (c-1)
        *(float4*)(cbox + (size_t)t * 4) = make_float4(bx1, by1, bx2, by2);
        csc[t] = s;
        bool valid = s > SCORE_T;
        unsigned int sb = __float_as_uint(s);
        int m = t - img * NCAND;
        ckey[t] = valid ? (((unsigned long long)sb << 32) | (unsigned int)(NCAND - 1 - m)) : 0ull;
    }
}

// ---------------- rank: uniform-j broadcast compares, 80 blocks ----------------
__global__ __launch_bounds__(256) void rank_k(const float* __restrict__ cbox,
                                              const float* __restrict__ csc,
                                              const unsigned long long* __restrict__ ckey,
                                              float* __restrict__ sbox, float* __restrict__ ssc,
                                              int* __restrict__ sm, int* __restrict__ vcount) {
    int img = blockIdx.x / 40;
    int seg = blockIdx.x % 40;
    int base = img * NCAND;
    int lm = threadIdx.x & 63;
    int chunk = threadIdx.x >> 6;
    int m = seg * 64 + lm;
    __shared__ __align__(16) unsigned long long keys[NCAND];
    for (int j = threadIdx.x; j < NCAND; j += 256) keys[j] = ckey[base + j];
    unsigned long long mykey = ckey[base + m];
    float s = csc[base + m];
    bool valid = s > SCORE_T;
    __syncthreads();
    const ulonglong2* kp = (const ulonglong2*)&keys[chunk * 640];
    int r = 0;
#pragma unroll 4
    for (int j = 0; j < 320; ++j) {
        ulonglong2 kk = kp[j];
        r += (kk.x > mykey) ? 1 : 0;
        r += (kk.y > mykey) ? 1 : 0;
    }
    __shared__ int part[4][64];
    part[chunk][lm] = r;
    __syncthreads();
    if (chunk == 0) {
        int rank = part[0][lm] + part[1][lm] + part[2][lm] + part[3][lm];
        if (valid) {
            int o = base + rank;
            *(float4*)(sbox + (size_t)o * 4) = *(const float4*)(cbox + (size_t)(base + m) * 4);
            ssc[o] = s;
            sm[o] = m;
        }
    }
    int cnt = __syncthreads_count((chunk == 0) && valid);
    if (threadIdx.x == 0) atomicAdd(&vcount[img], cnt);
}

// ---------------- per-(image,class) greedy NMS ----------------
__global__ __launch_bounds__(64) void nms_k(const int* __restrict__ sm,
                                            const float* __restrict__ sbox,
                                            const int* __restrict__ vcount,
                                            int* __restrict__ skeep) {
    int bid = blockIdx.x;
    int img = bid / 20;
    int cls = bid % 20 + 1;
    int V = vcount[img];
    __shared__ float lx1[128], ly1[128], lx2[128], ly2[128];
    __shared__ int lpos[128];
    __shared__ int lcnt;
    __shared__ int keepL[128];
    int lane = threadIdx.x;
    if (lane == 0) lcnt = 0;
    __syncthreads();
    for (int p0 = 0; p0 < V; p0 += 64) {
        int p = p0 + lane;
        bool pred = false;
        if (p < V) {
            int m = sm[img * NCAND + p];
            pred = (m % 20 + 1) == cls;
        }
        unsigned long long mask = __ballot(pred);
        int base = lcnt;
        if (pred) {
            int idx = base + __popcll(mask & ((1ull << lane) - 1ull));
            const float* bx = sbox + (size_t)(img * NCAND + (p0 + lane)) * 4;
            lx1[idx] = bx[0]; ly1[idx] = bx[1]; lx2[idx] = bx[2]; ly2[idx] = bx[3];
            lpos[idx] = p0 + lane;
        }
        __syncthreads();
        if (lane == 0) lcnt += (int)__popcll(mask);
        __syncthreads();
    }
    int C = lcnt;
    for (int j = lane; j < 128; j += 64) keepL[j] = 1;
    __syncthreads();
    for (int i = 0; i < C; ++i) {
        __syncthreads();
        if (keepL[i] == 0) continue;
        float X1 = lx1[i], Y1 = ly1[i], X2 = lx2[i], Y2 = ly2[i];
        float ai = (X2 - X1) * (Y2 - Y1);
        for (int j = i + 1 + lane; j < C; j += 64) {
            if (keepL[j]) {
                float xi1 = fmaxf(X1, lx1[j]);
                float yi1 = fmaxf(Y1, ly1[j]);
                float xi2 = fminf(X2, lx2[j]);
                float yi2 = fminf(Y2, ly2[j]);
                float inter = fmaxf(xi2 - xi1, 0.f) * fmaxf(yi2 - yi1, 0.f);
                float aj = (lx2[j] - lx1[j]) * (ly2[j] - ly1[j]);
                float iou = inter / (ai + aj - inter + 1e-9f);
                if (iou > NMS_T) keepL[j] = 0;
            }
        }
    }
    __syncthreads();
    for (int j = lane; j < C; j += 64) skeep[img * NCAND + lpos[j]] = keepL[j];
}

// ---------------- writer: prefix-scan kept, emit top-100 ----------------
__global__ __launch_bounds__(256) void write_k(const float* __restrict__ sbox,
                                               const float* __restrict__ ssc,
                                               const int* __restrict__ sm,
                                               const int* __restrict__ skeep,
                                               const int* __restrict__ vcount,
                                               float* __restrict__ out) {
    int img = blockIdx.x;
    int tid = threadIdx.x;
    float* ob = out + img * MAXDET * 4;
    float* os = out + BATCH * MAXDET * 4 + img * MAXDET;
    float* ol = out + BATCH * MAXDET * 5 + img * MAXDET;
    for (int i = tid; i < MAXDET * 4; i += 256) ob[i] = 0.0f;
    for (int i = tid; i < MAXDET; i += 256) { os[i] = 0.0f; ol[i] = 0.0f; }
    __syncthreads();
    int V = vcount[img];
    int chunk = (V + 255) / 256;
    int lo = tid * chunk, hi = min(lo + chunk, V);
    int cnt = 0;
    for (int p = lo; p < hi; ++p) cnt += skeep[img * NCAND + p];
    __shared__ int cs[256];
    __shared__ int pre[256];
    cs[tid] = cnt;
    __syncthreads();
    if (tid == 0) {
        int run = 0;
        for (int t = 0; t < 256; ++t) { pre[t] = run; run += cs[t]; }
    }
    __syncthreads();
    int r = pre[tid];
    for (int p = lo; p < hi; ++p) {
        if (skeep[img * NCAND + p]) {
            if (r < MAXDET) {
                const float* bx = sbox + (size_t)(img * NCAND + p) * 4;
                ob[r * 4 + 0] = bx[0]; ob[r * 4 + 1] = bx[1];
                ob[r * 4 + 2] = bx[2]; ob[r * 4 + 3] = bx[3];
                os[r] = ssc[img * NCAND + p];
                ol[r] = (float)(sm[img * NCAND + p] % 20 + 1);
            }
            ++r;
        }
    }
}

extern "C" void kernel_launch(void* const* d_in, const int* in_sizes, int n_in,
                              void* d_out, int out_size, void* d_ws, size_t ws_size,
                              hipStream_t stream) {
    const float* features  = (const float*)d_in[0];
    const float* proposals = (const float*)d_in[1];
    const int*   img_sizes = (const int*)d_in[2];
    const float* W1 = (const float*)d_in[3];
    const float* b1 = (const float*)d_in[4];
    const float* W2 = (const float*)d_in[5];
    const float* b2 = (const float*)d_in[6];
    const float* Wc = (const float*)d_in[7];
    const float* bc = (const float*)d_in[8];
    const float* Wb = (const float*)d_in[9];
    const float* bb = (const float*)d_in[10];
    float* out = (float*)d_out;

    float* ws = (float*)d_ws;
    float* roi   = ws;                        // 256*12544
    float* x1    = roi + 3211264;             // 262144
    float* cpart = x1 + 262144;               // 16 * 262144
    float* featT = cpart;                     // aliases cpart: dead before FC1 writes it
    float* cbox  = cpart + 16 * 262144;       // 20480
    float* csc   = cbox + 20480;              // 5120
    unsigned long long* ckey = (unsigned long long*)(csc + 5120);  // 5120 u64
    float* sbox  = csc + 5120 + 10240;        // 20480
    float* ssc   = sbox + 20480;              // 5120
    int*   sm    = (int*)(ssc + 5120);        // 5120
    int*   skeep = sm + 5120;                 // 5120
    int*   vcnt  = skeep + 5120;              // 2

    hipLaunchKernelGGL(transpose_feat, dim3(32, 8, 2), dim3(256), 0, stream, features, featT);
    hipLaunchKernelGGL(roi_align_tr, dim3(NROI * 2), dim3(256), 0, stream, featT, proposals, roi);
    // FC1: 256 x 12544 -> 1024, tile 128x128, split-K=16
    hipLaunchKernelGGL(gemm_tn_part, dim3(8, 2, 16), dim3(256), 0, stream, roi, W1, cpart, NROI, HID, FEAT_DIM);
    hipLaunchKernelGGL(reduce_bias_relu, dim3(256), dim3(256), 0, stream, cpart, b1, x1, NROI, HID, 16);
    // FC2: 256 x 1024 -> 1024, split-K=16 (cpart reused; reduced inside heads_cand_k)
    hipLaunchKernelGGL(gemm_tn_part, dim3(8, 2, 16), dim3(256), 0, stream, x1, W2, cpart, NROI, HID, HID);
    hipLaunchKernelGGL(heads_cand_k, dim3(NROI), dim3(256), 0, stream, cpart, b2, Wc, bc, Wb, bb,
                       proposals, img_sizes, cbox, csc, ckey, vcnt);
    hipLaunchKernelGGL(rank_k, dim3(80), dim3(256), 0, stream, cbox, csc, ckey, sbox, ssc, sm, vcnt);
    hipLaunchKernelGGL(nms_k, dim3(BATCH * 20), dim3(64), 0, stream, sm, sbox, vcnt, skeep);
    hipLaunchKernelGGL(write_k, dim3(BATCH), dim3(256), 0, stream, sbox, ssc, sm, skeep, vcnt, out);
}